// Round 1
// baseline (327.114 us; speedup 1.0000x reference)
//
#include <hip/hip_runtime.h>
#include <stdint.h>

typedef unsigned short u16;
typedef __attribute__((ext_vector_type(8))) short bf16x8;
typedef __attribute__((ext_vector_type(4))) float f32x4;

#define LOG2E 1.4426950408889634f

__device__ __forceinline__ float bf2f(u16 u) {
    union { uint32_t i; float f; } v; v.i = ((uint32_t)u) << 16; return v.f;
}
__device__ __forceinline__ u16 f2bf(float f) {
    union { float f; uint32_t i; } v; v.f = f;
    uint32_t i = v.i;
    return (u16)((i + 0x7FFF + ((i >> 16) & 1)) >> 16);
}
__device__ __forceinline__ int imin(int a, int b) { return a < b ? a : b; }
__device__ __forceinline__ int imax(int a, int b) { return a > b ? a : b; }

// ---------------------------------------------------------------- rope table
// tab[n][j][2] = {cos,sin}(theta), j in [0,32); theta dup'd for j>=32.
__global__ void k_rope_table(float* __restrict__ tab) {
    int t = blockIdx.x * 256 + threadIdx.x;
    if (t >= 2304 * 32) return;
    int n = t >> 5, j = t & 31;
    int gh = n / 48, gw = n % 48;
    float f = (float)(j & 15);
    float coord = (j < 16) ? (float)gh : (float)gw;
    float inv = exp2f(-f * (13.287712379549449f / 16.0f)); // 10000^(-f/16)
    float th = coord * inv;
    tab[t * 2 + 0] = cosf(th);
    tab[t * 2 + 1] = sinf(th);
}

// ---------------------------------------------------------------- x -> bf16
__global__ void k_convert_x(const float* __restrict__ x, u16* __restrict__ xb, int total4) {
    int t = blockIdx.x * 256 + threadIdx.x;
    if (t >= total4) return;
    float4 v = ((const float4*)x)[t];
    ushort4 o;
    o.x = f2bf(v.x); o.y = f2bf(v.y); o.z = f2bf(v.z); o.w = f2bf(v.w);
    ((ushort4*)xb)[t] = o;
}

// ------------------------------------------- weights -> bf16, transposed [n][k]
// n-space: [0,1024)Wq [1024,1536)Wk [1536,1792)Wv1 [1792,2048)Wv2 -> WCT[2048][512]
//          [2048,2560) Wp -> WPT[512][512]
__global__ void k_transpose_w(const float* __restrict__ Wq, const float* __restrict__ Wk,
                              const float* __restrict__ Wv1, const float* __restrict__ Wv2,
                              const float* __restrict__ Wp,
                              u16* __restrict__ WCT, u16* __restrict__ WPT) {
    __shared__ u16 tile[64][65];
    int n0 = blockIdx.x * 64;
    int k0 = blockIdx.y * 64;
    int c = threadIdx.x & 63;
    int rr = threadIdx.x >> 6;
    const float* src; int stride; int roff; u16* dst; int nb;
    if (n0 < 1024)      { src = Wq;  stride = 1024; roff = 0;    dst = WCT; nb = n0; }
    else if (n0 < 1536) { src = Wk;  stride = 512;  roff = 1024; dst = WCT; nb = n0; }
    else if (n0 < 1792) { src = Wv1; stride = 256;  roff = 1536; dst = WCT; nb = n0; }
    else if (n0 < 2048) { src = Wv2; stride = 256;  roff = 1792; dst = WCT; nb = n0; }
    else                { src = Wp;  stride = 512;  roff = 2048; dst = WPT; nb = n0 - 2048; }
    int scol = n0 + c - roff;
#pragma unroll
    for (int i = 0; i < 16; ++i) {
        int k = rr * 16 + i;
        tile[c][k] = f2bf(src[(size_t)(k0 + k) * stride + scol]);
    }
    __syncthreads();
    int kk = threadIdx.x & 63;
    int c4 = threadIdx.x >> 6;
#pragma unroll
    for (int i = 0; i < 16; ++i) {
        int nl = c4 * 16 + i;
        dst[(size_t)(nb + nl) * 512 + k0 + kk] = tile[nl][kk];
    }
}

// ---------------------------------------------------------------- GEMM (BT form)
// C[M][N] = A[M][512] * BT[N][512]^T ; 128x128 tile, BK=64, 4 waves, swizzled LDS.
template <bool OUT_F32>
__global__ __launch_bounds__(256) void k_gemm_bt(
    const u16* __restrict__ A, const u16* __restrict__ BT,
    void* __restrict__ Cout, const float* __restrict__ bias, int N) {
    __shared__ u16 Asw[128 * 64];
    __shared__ u16 Bsw[128 * 64];
    const int K = 512;
    int m0 = blockIdx.y * 128;
    int n0 = blockIdx.x * 128;
    int tid = threadIdx.x;
    int lane = tid & 63, w = tid >> 6;
    int wm = w >> 1, wn = w & 1;
    int li = lane & 15, g = lane >> 4;
    f32x4 zero4 = {0.f, 0.f, 0.f, 0.f};
    f32x4 acc[4][4];
#pragma unroll
    for (int mi = 0; mi < 4; ++mi)
#pragma unroll
        for (int ni = 0; ni < 4; ++ni) acc[mi][ni] = zero4;

    for (int k0 = 0; k0 < K; k0 += 64) {
        __syncthreads();
#pragma unroll
        for (int p = 0; p < 4; ++p) {
            int cidx = p * 256 + tid;          // 0..1023 chunk id
            int r = cidx >> 3, j = cidx & 7;
            int jj = j ^ (r & 7);              // source k-chunk for slot j
            uint4 va = *(const uint4*)(A + (size_t)(m0 + r) * K + k0 + jj * 8);
            *(uint4*)((char*)Asw + r * 128 + j * 16) = va;
            uint4 vb = *(const uint4*)(BT + (size_t)(n0 + r) * K + k0 + jj * 8);
            *(uint4*)((char*)Bsw + r * 128 + j * 16) = vb;
        }
        __syncthreads();
#pragma unroll
        for (int ks = 0; ks < 2; ++ks) {
            bf16x8 af[4], bfr[4];
#pragma unroll
            for (int mi = 0; mi < 4; ++mi) {
                int r = wm * 64 + mi * 16 + li;
                int kc = ks * 4 + g;
                af[mi] = *(const bf16x8*)((const char*)Asw + r * 128 + ((kc ^ (r & 7)) * 16));
            }
#pragma unroll
            for (int ni = 0; ni < 4; ++ni) {
                int r = wn * 64 + ni * 16 + li;
                int kc = ks * 4 + g;
                bfr[ni] = *(const bf16x8*)((const char*)Bsw + r * 128 + ((kc ^ (r & 7)) * 16));
            }
#pragma unroll
            for (int mi = 0; mi < 4; ++mi)
#pragma unroll
                for (int ni = 0; ni < 4; ++ni)
                    acc[mi][ni] = __builtin_amdgcn_mfma_f32_16x16x32_bf16(af[mi], bfr[ni], acc[mi][ni], 0, 0, 0);
        }
    }
#pragma unroll
    for (int mi = 0; mi < 4; ++mi)
#pragma unroll
        for (int ni = 0; ni < 4; ++ni) {
#pragma unroll
            for (int r = 0; r < 4; ++r) {
                int row = m0 + wm * 64 + mi * 16 + g * 4 + r;
                int col = n0 + wn * 64 + ni * 16 + li;
                float v = acc[mi][ni][r];
                if constexpr (OUT_F32) {
                    ((float*)Cout)[(size_t)row * N + col] = v + bias[col];
                } else {
                    ((u16*)Cout)[(size_t)row * N + col] = f2bf(v);
                }
            }
        }
}

// ------------------------------------------------- L2 norm + RoPE, head split
// one wave per 64-vector; 24 slots per (b,n): 8 q1, 8 q2, 4 k1, 4 k2
__global__ void k_norm_rope(const u16* __restrict__ qall, const float* __restrict__ tab,
                            u16* __restrict__ Q1, u16* __restrict__ Q2,
                            u16* __restrict__ K1, u16* __restrict__ K2) {
    int wv = (blockIdx.x * blockDim.x + threadIdx.x) >> 6;
    int lane = threadIdx.x & 63;
    if (wv >= 9216 * 24) return;
    int row = wv / 24, slot = wv % 24;
    int b = row / 2304, n = row % 2304;
    int col0; u16* out; size_t obase;
    if (slot < 8)       { col0 = slot * 64;              out = Q1; obase = ((size_t)(b * 8 + slot) * 2304 + n) * 64; }
    else if (slot < 16) { col0 = 512 + (slot - 8) * 64;  out = Q2; obase = ((size_t)(b * 8 + (slot - 8)) * 2304 + n) * 64; }
    else if (slot < 20) { col0 = 1024 + (slot - 16) * 64; out = K1; obase = ((size_t)(b * 4 + (slot - 16)) * 2304 + n) * 64; }
    else                { col0 = 1280 + (slot - 20) * 64; out = K2; obase = ((size_t)(b * 4 + (slot - 20)) * 2304 + n) * 64; }
    float x = bf2f(qall[(size_t)row * 2048 + col0 + lane]);
    float ss = x * x;
#pragma unroll
    for (int m = 1; m < 64; m <<= 1) ss += __shfl_xor(ss, m, 64);
    x *= 1.0f / sqrtf(ss + 1e-12f);
    float p = __shfl_xor(x, 32, 64);
    const float* tp = tab + ((size_t)n * 32 + (lane & 31)) * 2;
    float c = tp[0], s = tp[1];
    float y = (lane < 32) ? (x * c - p * s) : (x * c + p * s);
    out[obase + lane] = f2bf(y);
}

// ------------------------------------------------- V -> VT[b][hkv][d][n]
__global__ void k_v_transpose(const u16* __restrict__ qall, u16* __restrict__ VT1, u16* __restrict__ VT2) {
    __shared__ u16 tile[64][72];
    int nt = blockIdx.x, id = blockIdx.y;
    int br = id & 1, hkv = (id >> 1) & 3, b = id >> 3;
    int col0 = 1536 + br * 256 + hkv * 64;
    int n0 = nt * 64;
    int t = threadIdx.x;
#pragma unroll
    for (int pass = 0; pass < 2; ++pass) {
        int idx = pass * 256 + t;
        int nl = idx >> 3, ch = idx & 7;
        uint4 v = *(const uint4*)(qall + ((size_t)(b * 2304 + n0 + nl)) * 2048 + col0 + ch * 8);
        const u16* pv = (const u16*)&v;
#pragma unroll
        for (int i = 0; i < 8; ++i) tile[ch * 8 + i][nl] = pv[i];
    }
    __syncthreads();
    u16* VT = br ? VT2 : VT1;
    size_t base = ((size_t)(b * 4 + hkv) * 64) * 2304;
    int d = t >> 2, part = t & 3;
    uint4* dst = (uint4*)(VT + base + (size_t)d * 2304 + n0 + part * 16);
    dst[0] = *(const uint4*)&tile[d][part * 16];
    dst[1] = *(const uint4*)&tile[d][part * 16 + 8];
}

// ------------------------------------------------- differential windowed attention
// block = (b, hkv, qh); 12 waves: beta(branch) x h2(q-head) x mu(m-tile of 16 q)
__global__ __launch_bounds__(768) void k_attention(
    const u16* __restrict__ Q1, const u16* __restrict__ Q2,
    const u16* __restrict__ K1, const u16* __restrict__ K2,
    const u16* __restrict__ VT1, const u16* __restrict__ VT2,
    const float* __restrict__ lambda_p, u16* __restrict__ AOUT) {
    __shared__ __align__(16) char lds[53248];
    // [0,12288)  K tiles: 2 x [48 rows][128B], swizzled
    // [12288,28672) VT tiles: 2 x [64 rows][128B], swizzled (key-chunks 6,7 = pad)
    // [28672,53248) P: 12 waves x [16 rows][128B], swizzled
    char* Klds = lds;
    char* Vlds = lds + 12288;
    int tid = threadIdx.x;
    int lane = tid & 63, w = tid >> 6;
    int beta = w & 1, h2 = (w >> 1) & 1, mu = w >> 2;
    char* Plds = lds + 28672 + w * 2048;
    int bid = blockIdx.x;
    int qh = bid % 48, hkv = (bid / 48) % 4, b = bid / 192;
    int h = hkv * 2 + h2;
    int li = lane & 15, g = lane >> 4;

    uint4 z4; z4.x = z4.y = z4.z = z4.w = 0u;
    // zero VT pad chunks (6,7) for both branches
    if (tid < 256) {
        int brz = tid >> 7, d = (tid >> 1) & 63, ch = 6 + (tid & 1);
        *(uint4*)(Vlds + brz * 8192 + d * 128 + ((ch ^ (d & 7)) * 16)) = z4;
    }
    // zero P pad (cols 48..63)
    if (lane < 32) {
        int r = lane >> 1, ch = 6 + (lane & 1);
        *(uint4*)(Plds + r * 128 + ((ch ^ (r & 7)) * 16)) = z4;
    }

    const u16* Q  = beta ? Q2 : Q1;
    const u16* Kg = beta ? K2 : K1;
    const u16* Vg = beta ? VT2 : VT1;
    size_t qrow = ((size_t)(b * 8 + h) * 2304 + (size_t)qh * 48 + mu * 16 + li) * 64;
    bf16x8 qf0 = *(const bf16x8*)(Q + qrow + g * 8);
    bf16x8 qf1 = *(const bf16x8*)(Q + qrow + 32 + g * 8);

    f32x4 zero4 = {0.f, 0.f, 0.f, 0.f};
    f32x4 Oa[4];
#pragma unroll
    for (int dt = 0; dt < 4; ++dt) Oa[dt] = zero4;
    float mrun[4], lrun[4];
#pragma unroll
    for (int r = 0; r < 4; ++r) { mrun[r] = -1e30f; lrun[r] = 0.f; }

    int kh0 = imax(0, qh - 12), kh1 = imin(47, qh + 12);
    size_t kvbase = (size_t)(b * 4 + hkv);

    for (int kh = kh0; kh <= kh1; ++kh) {
        __syncthreads();
        { // stage K1,K2 row-block [48][64]
            int arr = tid / 384, lc = tid % 384;
            int r = lc >> 3, j = lc & 7;
            int jj = j ^ (r & 7);
            const u16* src = arr ? K2 : K1;
            uint4 v = *(const uint4*)(src + (kvbase * 2304 + (size_t)kh * 48 + r) * 64 + jj * 8);
            *(uint4*)(Klds + arr * 6144 + r * 128 + j * 16) = v;
        }
        { // stage VT1,VT2 [64][48] into 128B-pitch swizzled rows
            int arr = tid / 384, lc = tid % 384;
            int d = lc / 6, ch = lc % 6;
            int j = ch ^ (d & 7);
            const u16* src = arr ? VT2 : VT1;
            uint4 v = *(const uint4*)(src + (kvbase * 64 + d) * 2304 + (size_t)kh * 48 + ch * 8);
            *(uint4*)(Vlds + arr * 8192 + d * 128 + j * 16) = v;
        }
        __syncthreads();

        // S = Q K^T  (3 key-tiles of 16)
        char* Kb = Klds + beta * 6144;
        f32x4 S[3];
#pragma unroll
        for (int nt = 0; nt < 3; ++nt) {
            int r = nt * 16 + li;
            f32x4 s = zero4;
            bf16x8 k0f = *(const bf16x8*)(Kb + r * 128 + (((0 + g) ^ (r & 7)) * 16));
            s = __builtin_amdgcn_mfma_f32_16x16x32_bf16(qf0, k0f, s, 0, 0, 0);
            bf16x8 k1f = *(const bf16x8*)(Kb + r * 128 + (((4 + g) ^ (r & 7)) * 16));
            s = __builtin_amdgcn_mfma_f32_16x16x32_bf16(qf1, k1f, s, 0, 0, 0);
            S[nt] = s;
        }

        // mask + online softmax
        int qwbase = mu * 16 + g * 4;
        float sv[3][4], pmax[4];
#pragma unroll
        for (int r = 0; r < 4; ++r) pmax[r] = -1e30f;
#pragma unroll
        for (int nt = 0; nt < 3; ++nt)
#pragma unroll
            for (int r = 0; r < 4; ++r) {
                int qw = qwbase + r;
                int kw = nt * 16 + li;
                int dw = qw - kw; if (dw < 0) dw = -dw;
                float s = (dw <= 12) ? S[nt][r] * 0.125f : -1e30f;
                sv[nt][r] = s;
                pmax[r] = fmaxf(pmax[r], s);
            }
#pragma unroll
        for (int r = 0; r < 4; ++r) {
#pragma unroll
            for (int m = 1; m < 16; m <<= 1) pmax[r] = fmaxf(pmax[r], __shfl_xor(pmax[r], m, 64));
        }
        float fvec[4];
#pragma unroll
        for (int r = 0; r < 4; ++r) {
            float mnew = fmaxf(mrun[r], pmax[r]);
            fvec[r] = exp2f((mrun[r] - mnew) * LOG2E);
            mrun[r] = mnew;
        }
        float psum[4] = {0.f, 0.f, 0.f, 0.f};
        u16 pb[3][4];
#pragma unroll
        for (int nt = 0; nt < 3; ++nt)
#pragma unroll
            for (int r = 0; r < 4; ++r) {
                float p = exp2f((sv[nt][r] - mrun[r]) * LOG2E);
                u16 pq = f2bf(p);
                pb[nt][r] = pq;
                psum[r] += bf2f(pq);
            }
#pragma unroll
        for (int r = 0; r < 4; ++r) {
            float t = psum[r];
#pragma unroll
            for (int m = 1; m < 16; m <<= 1) t += __shfl_xor(t, m, 64);
            lrun[r] = lrun[r] * fvec[r] + t;
        }
#pragma unroll
        for (int dt = 0; dt < 4; ++dt)
#pragma unroll
            for (int r = 0; r < 4; ++r) Oa[dt][r] *= fvec[r];
        // write P (bf16) to wave-private swizzled LDS
#pragma unroll
        for (int nt = 0; nt < 3; ++nt)
#pragma unroll
            for (int r = 0; r < 4; ++r) {
                int row = g * 4 + r;
                int col = nt * 16 + li;
                int chunk = col >> 3, off = (col * 2) & 15;
                *(u16*)(Plds + row * 128 + ((chunk ^ (row & 7)) * 16) + off) = pb[nt][r];
            }
        // PV
        bf16x8 pf0 = *(const bf16x8*)(Plds + li * 128 + (((0 + g) ^ (li & 7)) * 16));
        bf16x8 pf1 = *(const bf16x8*)(Plds + li * 128 + (((4 + g) ^ (li & 7)) * 16));
        char* Vb = Vlds + beta * 8192;
#pragma unroll
        for (int dt = 0; dt < 4; ++dt) {
            int d = dt * 16 + li;
            bf16x8 v0 = *(const bf16x8*)(Vb + d * 128 + (((0 + g) ^ (d & 7)) * 16));
            Oa[dt] = __builtin_amdgcn_mfma_f32_16x16x32_bf16(pf0, v0, Oa[dt], 0, 0, 0);
            bf16x8 v1 = *(const bf16x8*)(Vb + d * 128 + (((4 + g) ^ (d & 7)) * 16));
            Oa[dt] = __builtin_amdgcn_mfma_f32_16x16x32_bf16(pf1, v1, Oa[dt], 0, 0, 0);
        }
    }

#pragma unroll
    for (int dt = 0; dt < 4; ++dt)
#pragma unroll
        for (int r = 0; r < 4; ++r) Oa[dt][r] /= lrun[r];

    __syncthreads();
    float* O2buf = (float*)lds; // overlay on K/VT region (24KB)
    if (beta == 1) {
        float* buf = O2buf + (h2 * 3 + mu) * 1024;
#pragma unroll
        for (int dt = 0; dt < 4; ++dt)
#pragma unroll
            for (int r = 0; r < 4; ++r) buf[(g * 4 + r) * 64 + dt * 16 + li] = Oa[dt][r];
    }
    __syncthreads();
    if (beta == 0) {
        float lam = 1.0f / (1.0f + expf(-lambda_p[h]));
        const float* buf = O2buf + (h2 * 3 + mu) * 1024;
#pragma unroll
        for (int dt = 0; dt < 4; ++dt)
#pragma unroll
            for (int r = 0; r < 4; ++r) {
                float o2 = buf[(g * 4 + r) * 64 + dt * 16 + li];
                float v = Oa[dt][r] - lam * o2;
                int n = qh * 48 + mu * 16 + g * 4 + r;
                int colc = h * 64 + dt * 16 + li;
                AOUT[((size_t)(b * 2304 + n)) * 512 + colc] = f2bf(v);
            }
    }
}

// ---------------------------------------------------------------- launcher
extern "C" void kernel_launch(void* const* d_in, const int* in_sizes, int n_in,
                              void* d_out, int out_size, void* d_ws, size_t ws_size,
                              hipStream_t stream) {
    const float* x        = (const float*)d_in[0];
    const float* Wq       = (const float*)d_in[1];
    const float* Wk       = (const float*)d_in[2];
    const float* Wv1      = (const float*)d_in[3];
    const float* Wv2      = (const float*)d_in[4];
    const float* lambda_p = (const float*)d_in[5];
    const float* Wp       = (const float*)d_in[6];
    const float* bp       = (const float*)d_in[7];

    char* ws = (char*)d_ws;
    size_t off = 0;
    auto alloc = [&](size_t bytes) { char* p = ws + off; off += (bytes + 255) & ~(size_t)255; return p; };
    float* rope = (float*)alloc((size_t)2304 * 32 * 2 * 4);      // 0.59 MB
    u16* XB     = (u16*)alloc((size_t)9216 * 512 * 2);           // 9.44 MB (reused as Q1)
    u16* WCT    = (u16*)alloc((size_t)2048 * 512 * 2);           // 2.10 MB
    u16* WPT    = (u16*)alloc((size_t)512 * 512 * 2);            // 0.52 MB
    u16* QALL   = (u16*)alloc((size_t)9216 * 2048 * 2);          // 37.75 MB (reused as AOUT)
    u16* Q2     = (u16*)alloc((size_t)4 * 8 * 2304 * 64 * 2);    // 9.44 MB
    u16* K1     = (u16*)alloc((size_t)4 * 4 * 2304 * 64 * 2);    // 4.72 MB
    u16* K2     = (u16*)alloc((size_t)4 * 4 * 2304 * 64 * 2);
    u16* VT1    = (u16*)alloc((size_t)4 * 4 * 64 * 2304 * 2);
    u16* VT2    = (u16*)alloc((size_t)4 * 4 * 64 * 2304 * 2);
    u16* Q1   = XB;    // safe overlay: XB dead after QKV GEMM, Q1 written after
    u16* AOUT = QALL;  // safe overlay: QALL dead after norm_rope + v_transpose

    k_rope_table<<<288, 256, 0, stream>>>(rope);
    k_convert_x<<<4608, 256, 0, stream>>>(x, XB, 9216 * 512 / 4);
    k_transpose_w<<<dim3(40, 8), 256, 0, stream>>>(Wq, Wk, Wv1, Wv2, Wp, WCT, WPT);
    k_gemm_bt<false><<<dim3(16, 72), 256, 0, stream>>>(XB, WCT, QALL, nullptr, 2048);
    k_norm_rope<<<55296, 256, 0, stream>>>(QALL, rope, Q1, Q2, K1, K2);
    k_v_transpose<<<dim3(36, 32), 256, 0, stream>>>(QALL, VT1, VT2);
    k_attention<<<768, 768, 0, stream>>>(Q1, Q2, K1, K2, VT1, VT2, lambda_p, AOUT);
    k_gemm_bt<true><<<dim3(4, 72), 256, 0, stream>>>(AOUT, WPT, d_out, bp, 512);
}

// Round 2
// 210.179 us; speedup vs baseline: 1.5564x; 1.5564x over previous
//
#include <hip/hip_runtime.h>
#include <stdint.h>

typedef unsigned short u16;
typedef __attribute__((ext_vector_type(8))) short bf16x8;
typedef __attribute__((ext_vector_type(4))) short bf16x4;
typedef __attribute__((ext_vector_type(4))) float f32x4;

#define LOG2E 1.4426950408889634f

__device__ __forceinline__ float bf2f(u16 u) {
    union { uint32_t i; float f; } v; v.i = ((uint32_t)u) << 16; return v.f;
}
__device__ __forceinline__ u16 f2bf(float f) {
    union { float f; uint32_t i; } v; v.f = f;
    uint32_t i = v.i;
    return (u16)((i + 0x7FFF + ((i >> 16) & 1)) >> 16);
}
__device__ __forceinline__ uint32_t cvt_pk_bf16(float a, float b) {
    uint32_t r;
    asm("v_cvt_pk_bf16_f32 %0, %1, %2" : "=v"(r) : "v"(a), "v"(b));
    return r;
}
__device__ __forceinline__ int imin(int a, int b) { return a < b ? a : b; }
__device__ __forceinline__ int imax(int a, int b) { return a > b ? a : b; }

union U8 { bf16x8 v; uint32_t u[4]; };

// ---------------------------------------------------------------- rope table
__global__ void k_rope_table(float* __restrict__ tab) {
    int t = blockIdx.x * 256 + threadIdx.x;
    if (t >= 2304 * 32) return;
    int n = t >> 5, j = t & 31;
    int gh = n / 48, gw = n % 48;
    float f = (float)(j & 15);
    float coord = (j < 16) ? (float)gh : (float)gw;
    float inv = exp2f(-f * (13.287712379549449f / 16.0f)); // 10000^(-f/16)
    float th = coord * inv;
    tab[t * 2 + 0] = cosf(th);
    tab[t * 2 + 1] = sinf(th);
}

// ---------------------------------------------------------------- x -> bf16
__global__ void k_convert_x(const float* __restrict__ x, u16* __restrict__ xb, int total4) {
    int t = blockIdx.x * 256 + threadIdx.x;
    if (t >= total4) return;
    float4 v = ((const float4*)x)[t];
    ushort4 o;
    o.x = f2bf(v.x); o.y = f2bf(v.y); o.z = f2bf(v.z); o.w = f2bf(v.w);
    ((ushort4*)xb)[t] = o;
}

// ------------------------------------------- weights -> bf16, transposed [n][k]
__global__ void k_transpose_w(const float* __restrict__ Wq, const float* __restrict__ Wk,
                              const float* __restrict__ Wv1, const float* __restrict__ Wv2,
                              const float* __restrict__ Wp,
                              u16* __restrict__ WCT, u16* __restrict__ WPT) {
    __shared__ u16 tile[64][65];
    int n0 = blockIdx.x * 64;
    int k0 = blockIdx.y * 64;
    int c = threadIdx.x & 63;
    int rr = threadIdx.x >> 6;
    const float* src; int stride; int roff; u16* dst; int nb;
    if (n0 < 1024)      { src = Wq;  stride = 1024; roff = 0;    dst = WCT; nb = n0; }
    else if (n0 < 1536) { src = Wk;  stride = 512;  roff = 1024; dst = WCT; nb = n0; }
    else if (n0 < 1792) { src = Wv1; stride = 256;  roff = 1536; dst = WCT; nb = n0; }
    else if (n0 < 2048) { src = Wv2; stride = 256;  roff = 1792; dst = WCT; nb = n0; }
    else                { src = Wp;  stride = 512;  roff = 2048; dst = WPT; nb = n0 - 2048; }
    int scol = n0 + c - roff;
#pragma unroll
    for (int i = 0; i < 16; ++i) {
        int k = rr * 16 + i;
        tile[c][k] = f2bf(src[(size_t)(k0 + k) * stride + scol]);
    }
    __syncthreads();
    int kk = threadIdx.x & 63;
    int c4 = threadIdx.x >> 6;
#pragma unroll
    for (int i = 0; i < 16; ++i) {
        int nl = c4 * 16 + i;
        dst[(size_t)(nb + nl) * 512 + k0 + kk] = tile[nl][kk];
    }
}

// ---------------------------------------------------------------- GEMM (BT form)
template <bool OUT_F32>
__global__ __launch_bounds__(256) void k_gemm_bt(
    const u16* __restrict__ A, const u16* __restrict__ BT,
    void* __restrict__ Cout, const float* __restrict__ bias, int N) {
    __shared__ u16 Asw[128 * 64];
    __shared__ u16 Bsw[128 * 64];
    const int K = 512;
    int m0 = blockIdx.y * 128;
    int n0 = blockIdx.x * 128;
    int tid = threadIdx.x;
    int lane = tid & 63, w = tid >> 6;
    int wm = w >> 1, wn = w & 1;
    int li = lane & 15, g = lane >> 4;
    f32x4 zero4 = {0.f, 0.f, 0.f, 0.f};
    f32x4 acc[4][4];
#pragma unroll
    for (int mi = 0; mi < 4; ++mi)
#pragma unroll
        for (int ni = 0; ni < 4; ++ni) acc[mi][ni] = zero4;

    for (int k0 = 0; k0 < K; k0 += 64) {
        __syncthreads();
#pragma unroll
        for (int p = 0; p < 4; ++p) {
            int cidx = p * 256 + tid;
            int r = cidx >> 3, j = cidx & 7;
            int jj = j ^ (r & 7);
            uint4 va = *(const uint4*)(A + (size_t)(m0 + r) * K + k0 + jj * 8);
            *(uint4*)((char*)Asw + r * 128 + j * 16) = va;
            uint4 vb = *(const uint4*)(BT + (size_t)(n0 + r) * K + k0 + jj * 8);
            *(uint4*)((char*)Bsw + r * 128 + j * 16) = vb;
        }
        __syncthreads();
#pragma unroll
        for (int ks = 0; ks < 2; ++ks) {
            bf16x8 af[4], bfr[4];
#pragma unroll
            for (int mi = 0; mi < 4; ++mi) {
                int r = wm * 64 + mi * 16 + li;
                int kc = ks * 4 + g;
                af[mi] = *(const bf16x8*)((const char*)Asw + r * 128 + ((kc ^ (r & 7)) * 16));
            }
#pragma unroll
            for (int ni = 0; ni < 4; ++ni) {
                int r = wn * 64 + ni * 16 + li;
                int kc = ks * 4 + g;
                bfr[ni] = *(const bf16x8*)((const char*)Bsw + r * 128 + ((kc ^ (r & 7)) * 16));
            }
#pragma unroll
            for (int mi = 0; mi < 4; ++mi)
#pragma unroll
                for (int ni = 0; ni < 4; ++ni)
                    acc[mi][ni] = __builtin_amdgcn_mfma_f32_16x16x32_bf16(af[mi], bfr[ni], acc[mi][ni], 0, 0, 0);
        }
    }
#pragma unroll
    for (int mi = 0; mi < 4; ++mi)
#pragma unroll
        for (int ni = 0; ni < 4; ++ni) {
#pragma unroll
            for (int r = 0; r < 4; ++r) {
                int row = m0 + wm * 64 + mi * 16 + g * 4 + r;
                int col = n0 + wn * 64 + ni * 16 + li;
                float v = acc[mi][ni][r];
                if constexpr (OUT_F32) {
                    ((float*)Cout)[(size_t)row * N + col] = v + bias[col];
                } else {
                    ((u16*)Cout)[(size_t)row * N + col] = f2bf(v);
                }
            }
        }
}

// ------------------------------------------------- L2 norm + RoPE, head split
__global__ void k_norm_rope(const u16* __restrict__ qall, const float* __restrict__ tab,
                            u16* __restrict__ Q1, u16* __restrict__ Q2,
                            u16* __restrict__ K1, u16* __restrict__ K2) {
    int wv = (blockIdx.x * blockDim.x + threadIdx.x) >> 6;
    int lane = threadIdx.x & 63;
    if (wv >= 9216 * 24) return;
    int row = wv / 24, slot = wv % 24;
    int b = row / 2304, n = row % 2304;
    int col0; u16* out; size_t obase;
    if (slot < 8)       { col0 = slot * 64;              out = Q1; obase = ((size_t)(b * 8 + slot) * 2304 + n) * 64; }
    else if (slot < 16) { col0 = 512 + (slot - 8) * 64;  out = Q2; obase = ((size_t)(b * 8 + (slot - 8)) * 2304 + n) * 64; }
    else if (slot < 20) { col0 = 1024 + (slot - 16) * 64; out = K1; obase = ((size_t)(b * 4 + (slot - 16)) * 2304 + n) * 64; }
    else                { col0 = 1280 + (slot - 20) * 64; out = K2; obase = ((size_t)(b * 4 + (slot - 20)) * 2304 + n) * 64; }
    float x = bf2f(qall[(size_t)row * 2048 + col0 + lane]);
    float ss = x * x;
#pragma unroll
    for (int m = 1; m < 64; m <<= 1) ss += __shfl_xor(ss, m, 64);
    x *= 1.0f / sqrtf(ss + 1e-12f);
    float p = __shfl_xor(x, 32, 64);
    const float* tp = tab + ((size_t)n * 32 + (lane & 31)) * 2;
    float c = tp[0], s = tp[1];
    float y = (lane < 32) ? (x * c - p * s) : (x * c + p * s);
    out[obase + lane] = f2bf(y);
}

// ------------------------------------------------- V -> VT[b][hkv][kh_tile][d=64][k=48]
__global__ void k_v_transpose(const u16* __restrict__ qall, u16* __restrict__ VT1, u16* __restrict__ VT2) {
    __shared__ u16 tile[64][52];
    int kt = blockIdx.x;          // 0..47 key tile
    int id = blockIdx.y;          // 0..31
    int br = id & 1, hkv = (id >> 1) & 3, b = id >> 3;
    int col0 = 1536 + br * 256 + hkv * 64;
    int t = threadIdx.x;
    for (int idx = t; idx < 384; idx += 256) {
        int nl = idx >> 3, ch = idx & 7;
        uint4 v = *(const uint4*)(qall + ((size_t)(b * 2304 + kt * 48 + nl)) * 2048 + col0 + ch * 8);
        const u16* pv = (const u16*)&v;
#pragma unroll
        for (int i = 0; i < 8; ++i) tile[ch * 8 + i][nl] = pv[i];
    }
    __syncthreads();
    u16* VT = br ? VT2 : VT1;
    size_t base = ((size_t)((b * 4 + hkv) * 48 + kt) * 64) * 48;
    int d = t >> 2, q4 = t & 3;
#pragma unroll
    for (int j = 0; j < 3; ++j)
        *(uint2*)(VT + base + d * 48 + q4 * 12 + j * 4) = *(const uint2*)&tile[d][q4 * 12 + j * 4];
}

// ------------------------------------------------- differential windowed attention
// wave = (b,hkv,qh,mu,beta) handling both h2 heads; no LDS/barriers in the loop.
template <int A, int NTT>
__device__ __forceinline__ void attn_step(
    const u16* __restrict__ kb, const u16* __restrict__ vb,
    const bf16x8 (&qf)[2][2], const float (&bias)[3][4],
    f32x4 (&Oa)[2][4], float (&sum)[2], int li, int g) {
    const float SC = 0.125f * LOG2E;
    bf16x8 kf[NTT][2];
#pragma unroll
    for (int t = 0; t < NTT; ++t)
#pragma unroll
        for (int s = 0; s < 2; ++s)
            kf[t][s] = *(const bf16x8*)(kb + (A + t) * 1024 + li * 64 + s * 32 + g * 8);
    U8 pa0[2], pa1[2];
#pragma unroll
    for (int h = 0; h < 2; ++h) {
        f32x4 S[NTT];
#pragma unroll
        for (int t = 0; t < NTT; ++t) {
            f32x4 z = {0.f, 0.f, 0.f, 0.f};
            z = __builtin_amdgcn_mfma_f32_16x16x32_bf16(kf[t][0], qf[h][0], z, 0, 0, 0);
            S[t] = __builtin_amdgcn_mfma_f32_16x16x32_bf16(kf[t][1], qf[h][1], z, 0, 0, 0);
        }
        uint32_t pk[NTT][2];
#pragma unroll
        for (int t = 0; t < NTT; ++t)
#pragma unroll
            for (int rp = 0; rp < 2; ++rp) {
                float p0 = exp2f(fmaf(S[t][2 * rp],     SC, bias[A + t][2 * rp]));
                float p1 = exp2f(fmaf(S[t][2 * rp + 1], SC, bias[A + t][2 * rp + 1]));
                sum[h] += p0 + p1;
                pk[t][rp] = cvt_pk_bf16(p0, p1);
            }
        pa0[h].u[0] = pk[0][0]; pa0[h].u[1] = pk[0][1];
        pa0[h].u[2] = pk[1][0]; pa0[h].u[3] = pk[1][1];
        if (NTT == 3) { pa1[h].u[0] = pk[2][0]; pa1[h].u[1] = pk[2][1]; pa1[h].u[2] = 0; pa1[h].u[3] = 0; }
    }
#pragma unroll
    for (int dt = 0; dt < 4; ++dt) {
        int doff = (dt * 16 + li) * 48;
        union { bf16x8 v; bf16x4 h[2]; } vf0, vf1;
        vf0.h[0] = *(const bf16x4*)(vb + doff + A * 16 + g * 4);
        vf0.h[1] = *(const bf16x4*)(vb + doff + (A + 1) * 16 + g * 4);
        if (NTT == 3) {
            vf1.h[0] = *(const bf16x4*)(vb + doff + 32 + g * 4);
            vf1.h[1] = vf1.h[0]; // multiplied by zero P
        }
#pragma unroll
        for (int h = 0; h < 2; ++h) {
            Oa[h][dt] = __builtin_amdgcn_mfma_f32_16x16x32_bf16(pa0[h].v, vf0.v, Oa[h][dt], 0, 0, 0);
            if (NTT == 3)
                Oa[h][dt] = __builtin_amdgcn_mfma_f32_16x16x32_bf16(pa1[h].v, vf1.v, Oa[h][dt], 0, 0, 0);
        }
    }
}

__global__ __launch_bounds__(128) void k_attention(
    const u16* __restrict__ Q1, const u16* __restrict__ Q2,
    const u16* __restrict__ K1, const u16* __restrict__ K2,
    const u16* __restrict__ VT1, const u16* __restrict__ VT2,
    const float* __restrict__ lambda_p, u16* __restrict__ AOUT) {
    __shared__ float obuf[2][16][64];
    int tid = threadIdx.x;
    int lane = tid & 63, beta = tid >> 6;
    int li = lane & 15, g = lane >> 4;
    // XCD swizzle: group the 144 blocks of one (b,hkv) on one XCD
    int hw = blockIdx.x;
    int l = (hw & 7) * 288 + (hw >> 3);
    int mu = l % 3, qh = (l / 3) % 48, kvb = l / 144;
    int hkv = kvb & 3, b = kvb >> 2;

    const u16* Qb = beta ? Q2 : Q1;
    const u16* Kb = beta ? K2 : K1;
    const u16* Vb = beta ? VT2 : VT1;

    bf16x8 qf[2][2];
#pragma unroll
    for (int h2 = 0; h2 < 2; ++h2)
#pragma unroll
        for (int s = 0; s < 2; ++s)
            qf[h2][s] = *(const bf16x8*)(Qb + ((size_t)(b * 8 + hkv * 2 + h2) * 2304
                            + qh * 48 + mu * 16 + li) * 64 + s * 32 + g * 8);

    float bias[3][4];
    int qw = mu * 16 + li;
#pragma unroll
    for (int t = 0; t < 3; ++t)
#pragma unroll
        for (int r = 0; r < 4; ++r) {
            int kw = t * 16 + 4 * g + r;
            int dw = qw - kw; if (dw < 0) dw = -dw;
            bias[t][r] = (dw <= 12) ? 0.0f : -INFINITY;
        }

    f32x4 zero4 = {0.f, 0.f, 0.f, 0.f};
    f32x4 Oa[2][4];
#pragma unroll
    for (int h = 0; h < 2; ++h)
#pragma unroll
        for (int dt = 0; dt < 4; ++dt) Oa[h][dt] = zero4;
    float sum[2] = {0.f, 0.f};

    int kh0 = imax(0, qh - 12), kh1 = imin(47, qh + 12);
    int niter = kh1 - kh0 + 1;
    const u16* kb = Kb + ((size_t)kvb * 2304 + kh0 * 48) * 64;
    const u16* vb = Vb + ((size_t)(kvb * 48 + kh0) * 64) * 48;

    if (mu == 1) {
        for (int i = 0; i < niter; ++i) {
            attn_step<0, 3>(kb, vb, qf, bias, Oa, sum, li, g);
            kb += 3072; vb += 3072;
        }
    } else if (mu == 0) {
        for (int i = 0; i < niter; ++i) {
            attn_step<0, 2>(kb, vb, qf, bias, Oa, sum, li, g);
            kb += 3072; vb += 3072;
        }
    } else {
        for (int i = 0; i < niter; ++i) {
            attn_step<1, 2>(kb, vb, qf, bias, Oa, sum, li, g);
            kb += 3072; vb += 3072;
        }
    }

    // finish row-sums: reduce over g groups, then fetch per-(4g+r) sums
    float inv[2][4];
#pragma unroll
    for (int h = 0; h < 2; ++h) {
        float s = sum[h];
        s += __shfl_xor(s, 16, 64);
        s += __shfl_xor(s, 32, 64);   // every lane: rowsum for q = li
#pragma unroll
        for (int r = 0; r < 4; ++r)
            inv[h][r] = 1.0f / __shfl(s, 4 * g + r, 64);
    }

    if (beta == 1) {
#pragma unroll
        for (int h = 0; h < 2; ++h)
#pragma unroll
            for (int dt = 0; dt < 4; ++dt)
#pragma unroll
                for (int r = 0; r < 4; ++r)
                    obuf[h][4 * g + r][dt * 16 + li] = Oa[h][dt][r] * inv[h][r];
    }
    __syncthreads();
    if (beta == 0) {
#pragma unroll
        for (int h = 0; h < 2; ++h) {
            float lam = 1.0f / (1.0f + expf(-lambda_p[hkv * 2 + h]));
#pragma unroll
            for (int dt = 0; dt < 4; ++dt)
#pragma unroll
                for (int r = 0; r < 4; ++r) {
                    float o1 = Oa[h][dt][r] * inv[h][r];
                    float o2 = obuf[h][4 * g + r][dt * 16 + li];
                    int n = qh * 48 + mu * 16 + 4 * g + r;
                    int colc = (hkv * 2 + h) * 64 + dt * 16 + li;
                    AOUT[((size_t)(b * 2304 + n)) * 512 + colc] = f2bf(o1 - lam * o2);
                }
        }
    }
}

// ---------------------------------------------------------------- launcher
extern "C" void kernel_launch(void* const* d_in, const int* in_sizes, int n_in,
                              void* d_out, int out_size, void* d_ws, size_t ws_size,
                              hipStream_t stream) {
    const float* x        = (const float*)d_in[0];
    const float* Wq       = (const float*)d_in[1];
    const float* Wk       = (const float*)d_in[2];
    const float* Wv1      = (const float*)d_in[3];
    const float* Wv2      = (const float*)d_in[4];
    const float* lambda_p = (const float*)d_in[5];
    const float* Wp       = (const float*)d_in[6];
    const float* bp       = (const float*)d_in[7];

    char* ws = (char*)d_ws;
    size_t off = 0;
    auto alloc = [&](size_t bytes) { char* p = ws + off; off += (bytes + 255) & ~(size_t)255; return p; };
    float* rope = (float*)alloc((size_t)2304 * 32 * 2 * 4);
    u16* XB     = (u16*)alloc((size_t)9216 * 512 * 2);
    u16* WCT    = (u16*)alloc((size_t)2048 * 512 * 2);
    u16* WPT    = (u16*)alloc((size_t)512 * 512 * 2);
    u16* QALL   = (u16*)alloc((size_t)9216 * 2048 * 2);
    u16* Q2     = (u16*)alloc((size_t)4 * 8 * 2304 * 64 * 2);
    u16* K1     = (u16*)alloc((size_t)4 * 4 * 2304 * 64 * 2);
    u16* K2     = (u16*)alloc((size_t)4 * 4 * 2304 * 64 * 2);
    u16* VT1    = (u16*)alloc((size_t)4 * 4 * 48 * 64 * 48 * 2);
    u16* VT2    = (u16*)alloc((size_t)4 * 4 * 48 * 64 * 48 * 2);
    u16* Q1   = XB;    // safe overlay: XB dead after QKV GEMM
    u16* AOUT = QALL;  // safe overlay: QALL dead after norm_rope + v_transpose

    k_rope_table<<<288, 256, 0, stream>>>(rope);
    k_convert_x<<<4608, 256, 0, stream>>>(x, XB, 9216 * 512 / 4);
    k_transpose_w<<<dim3(40, 8), 256, 0, stream>>>(Wq, Wk, Wv1, Wv2, Wp, WCT, WPT);
    k_gemm_bt<false><<<dim3(16, 72), 256, 0, stream>>>(XB, WCT, QALL, nullptr, 2048);
    k_norm_rope<<<55296, 256, 0, stream>>>(QALL, rope, Q1, Q2, K1, K2);
    k_v_transpose<<<dim3(48, 32), 256, 0, stream>>>(QALL, VT1, VT2);
    k_attention<<<2304, 128, 0, stream>>>(Q1, Q2, K1, K2, VT1, VT2, lambda_p, AOUT);
    k_gemm_bt<true><<<dim3(4, 72), 256, 0, stream>>>(AOUT, WPT, d_out, bp, 512);
}